// Round 4
// baseline (24744.496 us; speedup 1.0000x reference)
//
#include <hip/hip_runtime.h>
#include <hip/hip_bf16.h>
#include <math.h>

#define BB 64
#define SS 512
#define EE 256
#define HH 512
#define GG 2048   // 4H
#define NWG 256
#define HSTRIDE 32768                       // floats per phase: 128 cblk * 64 b * 4
#define DSTRIDE ((size_t)(SS+1)*HSTRIDE)    // floats per direction

// ---------------------------------------------------------------------------
// K_pre: fold dense + CRF kernel:  wde[tag][k] = sum_m Wd[k][m]*crfW[m][tag]
// ---------------------------------------------------------------------------
__global__ void k_wde(const float* __restrict__ Wd, const float* __restrict__ bd,
                      const float* __restrict__ crfW, const float* __restrict__ crfb,
                      float* __restrict__ wde, float* __restrict__ bde)
{
  const int idx = blockIdx.x*256 + threadIdx.x;
  if (idx < 9*1024) {
    const int tag = idx >> 10, k = idx & 1023;
    float s = 0.f;
    #pragma unroll
    for (int m = 0; m < 9; ++m) s += Wd[k*9 + m] * crfW[m*9 + tag];
    wde[idx] = s;
  }
  if (idx < 9) {
    float s = crfb[idx];
    #pragma unroll
    for (int m = 0; m < 9; ++m) s += bd[m]*crfW[m*9 + idx];
    bde[idx] = s;
  }
}

// ---------------------------------------------------------------------------
// K2: persistent fused bidirectional LSTM. 256 WGs = 2 dir x 128 col-chunks
// (4 h-cols), 256 threads. h layout [phase][cblk][b][4] (WG store = 1 KB
// contiguous; consumer chunk = 32 KB contiguous). Per-chunk producer
// counters (RMW lines) + rotating-root go-flags (broadcast lines, ring-16,
// monotonic). All cross-WG traffic = relaxed agent atomics (sc1, no L2
// flushes). LDS staged with swizzle P(b,k) to kill 4/8-way bank conflicts.
// ---------------------------------------------------------------------------
__global__ __launch_bounds__(256, 1) void k_lstm(
    const int* __restrict__ inputs, const float* __restrict__ emb,
    const float* __restrict__ Uf, const float* __restrict__ Ub,
    const float* __restrict__ Wf, const float* __restrict__ Wb,
    const float* __restrict__ bf, const float* __restrict__ bb2,
    float* __restrict__ h_all, unsigned int* __restrict__ bars)
{
  const int wg   = blockIdx.x;
  const int d    = wg >> 7;
  const int cblk = wg & 127;                 // h-cols cblk*4 .. +3
  const int hcown= cblk >> 5;                // my producer group (chunk)
  const float* __restrict__ U    = d ? Ub  : Uf;
  const float* __restrict__ W    = d ? Wb  : Wf;
  const float* __restrict__ bias = d ? bb2 : bf;
  float* __restrict__ h_d = h_all + (size_t)d * DSTRIDE;
  unsigned int* __restrict__ cnt = bars + (d*4 + hcown)*16;   // own-group counter line

  __shared__ float smem[10240];   // overlay: chunk [64][128] swizzled (32KB) / pbuf [512][20]
  __shared__ float Wl[4096];      // [cn][i][kcc][jj][g]
  __shared__ int   tok_l[64];

  const int tid  = threadIdx.x;
  const int bq   = tid >> 6;        // wave id = b quarter
  const int lane = tid & 63;
  const int kcc  = lane & 15;       // 16-way k split
  const int jj   = lane >> 4;       // which of the 4 h-cols
  const int ss4  = ((kcc >> 2) & 1) * 4;       // pi() offset for this lane's k-span

  // stage W slice once: Wl[cn*2048 + i*256 + kcc*16 + jj*4 + g]
  for (int e = 0; e < 16; ++e) {
    const int idx = tid*16 + e;
    const int g   = idx & 3;
    const int j2  = (idx >> 2) & 3;
    const int kc2 = (idx >> 4) & 15;
    const int i2  = (idx >> 8) & 7;
    const int cn2 = (idx >> 11) & 1;
    const int k   = cn2*128 + kc2*8 + i2;
    Wl[idx] = W[(size_t)k*GG + g*512 + cblk*4 + j2];
  }

  // U in registers: ureg[cn*8+i] = gates (i,f,g,o) at k=cn*128+kcc*8+i, col cblk*4+jj
  float4 ureg[32];
  #pragma unroll
  for (int cn = 0; cn < 4; ++cn)
    #pragma unroll
    for (int i = 0; i < 8; ++i) {
      const int k = cn*128 + kcc*8 + i;
      const float* ur = U + (size_t)k*GG + cblk*4 + jj;
      ureg[cn*8+i] = make_float4(ur[0], ur[512], ur[1024], ur[1536]);
    }

  // gate-phase statics (threads 0..127 own (b,col) pairs, fixed across steps)
  const int gq  = tid >> 5;        // 0..3
  const int gbl = (tid >> 2) & 7;  // 0..7
  const int gj  = tid & 3;         // col within chunk
  float bb[4] = {0.f,0.f,0.f,0.f};
  if (tid < 128) {
    #pragma unroll
    for (int g = 0; g < 4; ++g) bb[g] = bias[g*512 + cblk*4 + gj];
  }
  float cst0 = 0.f, cst1 = 0.f;    // c-state for b-half 0 / 1

  // staging statics: thread owns k-block scl*4.. of rows b = sbb*8 + j
  const int scl = tid >> 3;          // 0..31 (k-block)
  const int sbb = tid & 7;           // row-octet base
  const int sk  = scl * 4;
  const int swzP = (((sk ^ (((sk >> 5) & 1) << 2))) + sbb*8) & 127;  // P(b,k-block)

  for (int p = 0; p < 512; ++p) {
    const int t = d ? (511 - p) : p;
    const float* __restrict__ hprev = h_d + (size_t)p     * HSTRIDE;
    float* __restrict__ hnext       = h_d + (size_t)(p+1) * HSTRIDE + cblk*256;

    if (tid < 64) tok_l[tid] = inputs[tid*SS + t];
    __syncthreads();                 // tok ready; prev-step pbuf reads done

    float4 xr[8];
    unsigned long long hr[16];
    // prefetch x chunk 0
    #pragma unroll
    for (int j = 0; j < 8; ++j)
      xr[j] = *(const float4*)&emb[(size_t)tok_l[sbb*8 + j]*EE + sk];

    float part[16][4];
    #pragma unroll
    for (int bl=0;bl<16;++bl) { part[bl][0]=0.f; part[bl][1]=0.f; part[bl][2]=0.f; part[bl][3]=0.f; }

    // 6 chunks: cn 0..1 = x@W (K=256), cn 2..5 = h@U (K=512)
    #pragma unroll
    for (int cn = 0; cn < 6; ++cn) {
      // write prefetched regs -> smem (swizzled [b][P(k)])
      if (cn < 2) {
        #pragma unroll
        for (int j = 0; j < 8; ++j)
          *(float4*)&smem[(sbb*8 + j)*128 + swzP] = xr[j];
      } else {
        #pragma unroll
        for (int j = 0; j < 8; ++j) {
          float* dst = &smem[(sbb*8 + j)*128 + swzP];
          *(unsigned long long*)dst       = hr[2*j];
          *(unsigned long long*)(dst + 2) = hr[2*j+1];
        }
      }
      // go-flag waits: chunk0 by wave0 at cn==1, chunks 1-3 by waves 1-3 at cn==2
      if (p) {
        if (cn == 1 && bq == 0) {
          const unsigned int* gl = bars + 128 + ((d*4 + 0)*16 + (p & 15))*16;
          while (__hip_atomic_load(gl, __ATOMIC_RELAXED, __HIP_MEMORY_SCOPE_AGENT) < (unsigned)p)
            __builtin_amdgcn_s_sleep(1);
        }
        if (cn == 2 && bq != 0) {
          const unsigned int* gl = bars + 128 + ((d*4 + bq)*16 + (p & 15))*16;
          while (__hip_atomic_load(gl, __ATOMIC_RELAXED, __HIP_MEMORY_SCOPE_AGENT) < (unsigned)p)
            __builtin_amdgcn_s_sleep(1);
        }
      }
      __syncthreads();
      // prefetch next chunk (overlaps compute below)
      if (cn == 0) {
        #pragma unroll
        for (int j = 0; j < 8; ++j)
          xr[j] = *(const float4*)&emb[(size_t)tok_l[sbb*8 + j]*EE + 128 + sk];
      } else if (cn < 5) {
        const int hc = cn - 1;      // h chunk for iteration cn+1
        const float* src = hprev + hc*8192 + scl*256 + sbb*32;
        #pragma unroll
        for (int j = 0; j < 8; ++j) {
          const float* s4 = src + j*4;
          hr[2*j]   = __hip_atomic_load((const unsigned long long*)s4,
                         __ATOMIC_RELAXED, __HIP_MEMORY_SCOPE_AGENT);
          hr[2*j+1] = __hip_atomic_load((const unsigned long long*)(s4 + 2),
                         __ATOMIC_RELAXED, __HIP_MEMORY_SCOPE_AGENT);
        }
      }
      // compute chunk cn (reads via swizzle; 2-way max -> free)
      if (cn < 2) {
        float4 wv[8];
        #pragma unroll
        for (int i = 0; i < 8; ++i)
          wv[i] = *(const float4*)&Wl[cn*2048 + i*256 + kcc*16 + jj*4];
        #pragma unroll
        for (int bl = 0; bl < 16; ++bl) {
          const int row = bq*16 + bl;
          const int offr = ((row >> 3) & 7) * 8;
          const float4 ha = *(const float4*)&smem[row*128 + ((kcc*8 + ss4     + offr) & 127)];
          const float4 hb4= *(const float4*)&smem[row*128 + ((kcc*8 + 4 - ss4 + offr) & 127)];
          const float hv[8] = {ha.x,ha.y,ha.z,ha.w,hb4.x,hb4.y,hb4.z,hb4.w};
          #pragma unroll
          for (int i = 0; i < 8; ++i) {
            part[bl][0] += hv[i]*wv[i].x;
            part[bl][1] += hv[i]*wv[i].y;
            part[bl][2] += hv[i]*wv[i].z;
            part[bl][3] += hv[i]*wv[i].w;
          }
        }
      } else {
        #pragma unroll
        for (int bl = 0; bl < 16; ++bl) {
          const int row = bq*16 + bl;
          const int offr = ((row >> 3) & 7) * 8;
          const float4 ha = *(const float4*)&smem[row*128 + ((kcc*8 + ss4     + offr) & 127)];
          const float4 hb4= *(const float4*)&smem[row*128 + ((kcc*8 + 4 - ss4 + offr) & 127)];
          const float hv[8] = {ha.x,ha.y,ha.z,ha.w,hb4.x,hb4.y,hb4.z,hb4.w};
          #pragma unroll
          for (int i = 0; i < 8; ++i) {
            const float4 u = ureg[(cn-2)*8 + i];
            part[bl][0] += hv[i]*u.x;
            part[bl][1] += hv[i]*u.y;
            part[bl][2] += hv[i]*u.z;
            part[bl][3] += hv[i]*u.w;
          }
        }
      }
      __syncthreads();   // compute done; smem reusable
    }

    // reduce 16 k-partials + gates, two b-halves (pbuf overlays smem)
    #pragma unroll
    for (int h = 0; h < 2; ++h) {
      #pragma unroll
      for (int bl = 0; bl < 8; ++bl) {
        const int row = (bq*8 + bl)*16;
        #pragma unroll
        for (int g = 0; g < 4; ++g)
          smem[(row + g*4 + jj)*20 + kcc] = part[h*8 + bl][g];
      }
      __syncthreads();
      if (tid < 128) {
        const int b = gq*16 + h*8 + gbl;
        float z[4];
        #pragma unroll
        for (int g = 0; g < 4; ++g) {
          const float* pr = &smem[((gq*8 + gbl)*16 + g*4 + gj)*20];
          const float4 s0 = *(const float4*)pr;
          const float4 s1 = *(const float4*)(pr+4);
          const float4 s2 = *(const float4*)(pr+8);
          const float4 s3 = *(const float4*)(pr+12);
          z[g] = ((s0.x+s0.y)+(s0.z+s0.w)) + ((s1.x+s1.y)+(s1.z+s1.w))
               + ((s2.x+s2.y)+(s2.z+s2.w)) + ((s3.x+s3.y)+(s3.z+s3.w)) + bb[g];
        }
        const float ig = 1.f/(1.f + expf(-z[0]));
        const float fg = 1.f/(1.f + expf(-z[1]));
        const float tg = tanhf(z[2]);
        const float og = 1.f/(1.f + expf(-z[3]));
        float cs = h ? cst1 : cst0;
        cs = fg*cs + ig*tg;
        if (h) cst1 = cs; else cst0 = cs;
        // contiguous 1-KB block per WG, write-through (agent-visible, no flush)
        __hip_atomic_store(&hnext[b*4 + gj], og * tanhf(cs),
                           __ATOMIC_RELAXED, __HIP_MEMORY_SCOPE_AGENT);
      }
      __syncthreads();
    }

    // arrive: drain h stores, bump group counter; rotating root publishes go
    asm volatile("s_waitcnt vmcnt(0)" ::: "memory");
    __syncthreads();
    if (tid == 0) {
      __hip_atomic_fetch_add(cnt, 1u, __ATOMIC_RELAXED, __HIP_MEMORY_SCOPE_AGENT);
      if ((cblk & 31) == (p & 31)) {             // root for my group this step
        const unsigned int tgt = 32u*(unsigned)(p+1);
        while (__hip_atomic_load(cnt, __ATOMIC_RELAXED, __HIP_MEMORY_SCOPE_AGENT) < tgt)
          __builtin_amdgcn_s_sleep(1);
        unsigned int* gl = bars + 128 + ((d*4 + hcown)*16 + ((p+1) & 15))*16;
        __hip_atomic_store(gl, (unsigned)(p+1), __ATOMIC_RELAXED, __HIP_MEMORY_SCOPE_AGENT);
      }
    }
  }
}

// ---------------------------------------------------------------------------
// K3: pots[b][t][tag] = [h_fw(t), h_bw(t)] @ wde^T + bde (+ boundaries)
// h layout: [d][phase][cblk][b][4]
// ---------------------------------------------------------------------------
__global__ __launch_bounds__(256) void k_dense(
    const float* __restrict__ h_all, const float* __restrict__ wde,
    const float* __restrict__ bde, const float* __restrict__ lb,
    const float* __restrict__ rb, float* __restrict__ pots)
{
  const int wv   = threadIdx.x >> 6;
  const int lane = threadIdx.x & 63;
  const int tok  = blockIdx.x*4 + wv;          // 0..32767
  const int b = tok >> 9, t = tok & 511;
  const float* hf = h_all + (size_t)(t+1)*HSTRIDE;
  const float* hb = h_all + DSTRIDE + (size_t)(SS-t)*HSTRIDE;
  float hr[16];
  *(float4*)&hr[0]  = *(const float4*)&hf[(lane*2    )*256 + b*4];
  *(float4*)&hr[4]  = *(const float4*)&hf[(lane*2 + 1)*256 + b*4];
  *(float4*)&hr[8]  = *(const float4*)&hb[(lane*2    )*256 + b*4];
  *(float4*)&hr[12] = *(const float4*)&hb[(lane*2 + 1)*256 + b*4];
  float s[9];
  #pragma unroll
  for (int tg = 0; tg < 9; ++tg) {
    const float* w0 = wde + tg*1024 + lane*8;
    const float* w1 = w0 + 512;
    const float4 a0 = *(const float4*)w0, a1 = *(const float4*)(w0+4);
    const float4 b0 = *(const float4*)w1, b1 = *(const float4*)(w1+4);
    s[tg] = hr[0]*a0.x + hr[1]*a0.y + hr[2]*a0.z + hr[3]*a0.w
          + hr[4]*a1.x + hr[5]*a1.y + hr[6]*a1.z + hr[7]*a1.w
          + hr[8]*b0.x + hr[9]*b0.y + hr[10]*b0.z + hr[11]*b0.w
          + hr[12]*b1.x + hr[13]*b1.y + hr[14]*b1.z + hr[15]*b1.w;
  }
  #pragma unroll
  for (int tg = 0; tg < 9; ++tg) {
    #pragma unroll
    for (int off = 32; off > 0; off >>= 1) s[tg] += __shfl_xor(s[tg], off, 64);
  }
  if (lane < 9) {
    float v = s[lane] + bde[lane];
    if (t == 0)   v += lb[lane];
    if (t == 511) v += rb[lane];
    pots[(size_t)tok*9 + lane] = v;
  }
}

// ---------------------------------------------------------------------------
// K4: Viterbi decode. One wave per batch row.
// ---------------------------------------------------------------------------
__global__ __launch_bounds__(64) void k_viterbi(
    const float* __restrict__ pots, const float* __restrict__ trans,
    float* __restrict__ dec)
{
  const int b = blockIdx.x;
  const int lane = threadIdx.x;
  __shared__ unsigned char bp[511*9];
  __shared__ unsigned char tl[512];
  __shared__ float af[9];
  const float* pb = pots + (size_t)b*512*9;
  float tr[9];
  #pragma unroll
  for (int i = 0; i < 9; ++i) tr[i] = (lane < 9) ? trans[i*9 + lane] : 0.f;
  float alpha = (lane < 9) ? pb[lane] : -3e38f;
  for (int t = 1; t < 512; ++t) {
    float best = -3e38f; int bi = 0;
    #pragma unroll
    for (int i = 0; i < 9; ++i) {
      const float sc = __shfl(alpha, i, 64) + tr[i];
      if (sc > best) { best = sc; bi = i; }     // strict > keeps first max (jnp.argmax)
    }
    if (lane < 9) {
      bp[(t-1)*9 + lane] = (unsigned char)bi;
      alpha = best + pb[(size_t)t*9 + lane];
    }
  }
  if (lane < 9) af[lane] = alpha;
  __syncthreads();
  if (lane == 0) {
    int tg = 0; float bv = af[0];
    #pragma unroll
    for (int i = 1; i < 9; ++i) if (af[i] > bv) { bv = af[i]; tg = i; }
    tl[511] = (unsigned char)tg;
    for (int t = 510; t >= 0; --t) { tg = bp[t*9 + tg]; tl[t] = (unsigned char)tg; }
  }
  __syncthreads();
  for (int t = lane; t < 512; t += 64) dec[(size_t)b*512 + t] = (float)tl[t];
}

// ---------------------------------------------------------------------------
extern "C" void kernel_launch(void* const* d_in, const int* in_sizes, int n_in,
                              void* d_out, int out_size, void* d_ws, size_t ws_size,
                              hipStream_t stream)
{
  const int*   inputs = (const int*)  d_in[0];
  const float* emb    = (const float*)d_in[1];
  const float* Wf     = (const float*)d_in[2];
  const float* Uf     = (const float*)d_in[3];
  const float* bf     = (const float*)d_in[4];
  const float* Wb     = (const float*)d_in[5];
  const float* Ub     = (const float*)d_in[6];
  const float* bb2    = (const float*)d_in[7];
  const float* Wd     = (const float*)d_in[8];
  const float* bd     = (const float*)d_in[9];
  const float* crfW   = (const float*)d_in[10];
  const float* crfb   = (const float*)d_in[11];
  const float* trans  = (const float*)d_in[12];
  const float* lb     = (const float*)d_in[13];
  const float* rb     = (const float*)d_in[14];

  float* ws   = (float*)d_ws;
  unsigned int* bars = (unsigned int*)d_ws;           // first 16 KB: cnt + go lines
  float* hall = ws + 4096;                            // 2*513*32768 floats (~134.5 MB)
  float* wde  = hall + 2*DSTRIDE;                     // 9216 floats
  float* bde  = wde + 9216;                           // 16 floats

  float* dec  = (float*)d_out;                        // 32768 floats
  float* pots = dec + (size_t)BB*SS;                  // 294912 floats

  hipMemsetAsync(d_ws, 0, 16384, stream);
  hipMemsetAsync(hall, 0, (size_t)HSTRIDE*sizeof(float), stream);
  hipMemsetAsync(hall + DSTRIDE, 0, (size_t)HSTRIDE*sizeof(float), stream);

  k_wde<<<36, 256, 0, stream>>>(Wd, bd, crfW, crfb, wde, bde);

  {
    const int*   a0 = inputs; const float* a1 = emb;
    const float* a2 = Uf;  const float* a3 = Ub;
    const float* a4 = Wf;  const float* a5 = Wb;
    const float* a6 = bf;  const float* a7 = bb2;
    float* a8 = hall; unsigned int* a9 = bars;
    void* args[] = { &a0,&a1,&a2,&a3,&a4,&a5,&a6,&a7,&a8,&a9 };
    if (hipLaunchCooperativeKernel((void*)k_lstm, dim3(NWG), dim3(256),
                                   args, 0, stream) != hipSuccess) {
      k_lstm<<<NWG, 256, 0, stream>>>(inputs, emb, Uf, Ub, Wf, Wb, bf, bb2, hall, bars);
    }
  }

  k_dense<<<8192, 256, 0, stream>>>(hall, wde, bde, lb, rb, pots);
  k_viterbi<<<64, 64, 0, stream>>>(pots, trans, dec);
}

// Round 5
// 8601.331 us; speedup vs baseline: 2.8768x; 2.8768x over previous
//
#include <hip/hip_runtime.h>
#include <hip/hip_bf16.h>
#include <math.h>

#define BB 64
#define SS 512
#define EE 256
#define HH 512
#define GG 2048   // 4H
#define NWG 256
#define HSTRIDE 32768                       // floats per phase: 64 b * 512 k
#define DSTRIDE ((size_t)(SS+1)*HSTRIDE)    // floats per direction
#define SWZ(q) ((q) ^ (((q) >> 3) & 7))     // LDS quad swizzle

// ---------------------------------------------------------------------------
// K_pre: fold dense + CRF kernel:  wde[tag][k] = sum_m Wd[k][m]*crfW[m][tag]
// ---------------------------------------------------------------------------
__global__ void k_wde(const float* __restrict__ Wd, const float* __restrict__ bd,
                      const float* __restrict__ crfW, const float* __restrict__ crfb,
                      float* __restrict__ wde, float* __restrict__ bde)
{
  const int idx = blockIdx.x*256 + threadIdx.x;
  if (idx < 9*1024) {
    const int tag = idx >> 10, k = idx & 1023;
    float s = 0.f;
    #pragma unroll
    for (int m = 0; m < 9; ++m) s += Wd[k*9 + m] * crfW[m*9 + tag];
    wde[idx] = s;
  }
  if (idx < 9) {
    float s = crfb[idx];
    #pragma unroll
    for (int m = 0; m < 9; ++m) s += bd[m]*crfW[m*9 + idx];
    bde[idx] = s;
  }
}

// ---------------------------------------------------------------------------
// K2: persistent fused bidirectional LSTM.
// 256 WGs: wg -> d=(wg>>2)&1, bq=wg&3, cg=wg>>3 (0..31).
// WG tile = batch rows bq*16..+15  x  h-cols cg*16..+15 (all 4 gates).
// 8 independent groups (d,bq) of 32 WGs; sync = per-WG ready flag (no RMW).
// U (32k x 4g) and W (16k x 4g) slices in VGPRs; x+h staged in LDS with quad
// swizzle; k-reduction via register shuffle tree (no LDS, no extra syncs).
// h layout: h_all[d][phase 0..512][b 0..63][k 0..511]; phase 0 = zeros.
// Cross-WG h hand-off: relaxed agent atomics (L2-bypass, no cache flushes).
// ---------------------------------------------------------------------------
__global__ __launch_bounds__(256, 1) void k_lstm(
    const int* __restrict__ inputs, const float* __restrict__ emb,
    const float* __restrict__ Uf, const float* __restrict__ Ub,
    const float* __restrict__ Wf, const float* __restrict__ Wb,
    const float* __restrict__ bf, const float* __restrict__ bb2,
    float* __restrict__ h_all, unsigned int* __restrict__ bars)
{
  const int wg = blockIdx.x;
  const int d  = (wg >> 2) & 1;
  const int bq = wg & 3;
  const int cg = wg >> 3;                    // 0..31
  const float* __restrict__ U    = d ? Ub  : Uf;
  const float* __restrict__ W    = d ? Wb  : Wf;
  const float* __restrict__ bias = d ? bb2 : bf;
  float* __restrict__ h_d = h_all + (size_t)d * DSTRIDE;
  unsigned int* __restrict__ rdy = bars + (d*4 + bq)*64;   // 32 flags, 256-B region

  __shared__ float xs[4096];    // [16 b][256 k] quad-swizzled (16 KB)
  __shared__ float hs[8192];    // [16 b][512 k] quad-swizzled (32 KB)
  __shared__ int   tok_l[16];

  const int tid  = threadIdx.x;
  const int w    = tid >> 6;
  const int lane = tid & 63;
  const int kcc  = lane & 15;
  const int jj   = lane >> 4;
  const int col  = cg*16 + w*4 + jj;         // this thread's h-column

  // weights in registers: k-split 16-way by kcc
  float4 ureg[32];   // U[k = kcc*32+i][gates ifgo at col]
  #pragma unroll
  for (int i = 0; i < 32; ++i) {
    const float* ur = U + (size_t)(kcc*32 + i)*GG + col;
    ureg[i] = make_float4(ur[0], ur[512], ur[1024], ur[1536]);
  }
  float4 wreg[16];   // W[k = kcc*16+i][gates at col]
  #pragma unroll
  for (int i = 0; i < 16; ++i) {
    const float* wr = W + (size_t)(kcc*16 + i)*GG + col;
    wreg[i] = make_float4(wr[0], wr[512], wr[1024], wr[1536]);
  }
  const float4 breg = make_float4(bias[col], bias[512+col], bias[1024+col], bias[1536+col]);
  float cst = 0.f;                           // c-state for (b = bq*16+kcc, col)

  #pragma unroll 1
  for (int p = 0; p < 512; ++p) {
    const int t = d ? (511 - p) : p;
    const float* __restrict__ hp = h_d + (size_t)p     * HSTRIDE;
    float* __restrict__ hn       = h_d + (size_t)(p+1) * HSTRIDE;

    if (tid < 16) tok_l[tid] = inputs[(bq*16 + tid)*SS + t];
    __syncthreads();                         // tok ready; prev-step LDS reads done

    // stage x tile [16][256] (cached loads; shared rows dedup via L2)
    #pragma unroll
    for (int r = 0; r < 4; ++r) {
      const int q = r*256 + tid, b = q >> 6, qx = q & 63;
      const float4 v = *(const float4*)&emb[(size_t)tok_l[b]*EE + qx*4];
      *(float4*)&xs[b*256 + SWZ(qx)*4] = v;
    }

    // wave 0 polls the 32 producer flags of this group (h(p) ready)
    if (p && w == 0) {
      for (;;) {
        unsigned int v = 0xFFFFFFFFu;
        if (lane < 32)
          v = __hip_atomic_load(&rdy[lane], __ATOMIC_RELAXED, __HIP_MEMORY_SCOPE_AGENT);
        if (__all((int)(v >= (unsigned)p))) break;
        __builtin_amdgcn_s_sleep(2);
      }
    }
    __syncthreads();                         // xs ready + h(p) ready

    // issue h(p) loads (L2-bypass), latency hidden by x@W below
    unsigned long long hld[16];
    #pragma unroll
    for (int r = 0; r < 8; ++r) {
      const int q = r*256 + tid, b = q >> 7, qh = q & 127;
      const float* src = hp + (size_t)(bq*16 + b)*HH + qh*4;
      hld[2*r]   = __hip_atomic_load((const unsigned long long*)src,
                      __ATOMIC_RELAXED, __HIP_MEMORY_SCOPE_AGENT);
      hld[2*r+1] = __hip_atomic_load((const unsigned long long*)(src + 2),
                      __ATOMIC_RELAXED, __HIP_MEMORY_SCOPE_AGENT);
    }

    float part[16][4];
    #pragma unroll
    for (int b = 0; b < 16; ++b) { part[b][0]=0.f; part[b][1]=0.f; part[b][2]=0.f; part[b][3]=0.f; }

    // x @ W  (K = 256, 16 k per thread)
    #pragma unroll
    for (int b = 0; b < 16; ++b) {
      const float* xrow = &xs[b*256];
      #pragma unroll
      for (int i = 0; i < 4; ++i) {
        const int q = kcc*4 + i;
        const float4 hv = *(const float4*)&xrow[SWZ(q)*4];
        const float4 w0 = wreg[i*4+0], w1 = wreg[i*4+1], w2 = wreg[i*4+2], w3 = wreg[i*4+3];
        part[b][0] += hv.x*w0.x + hv.y*w1.x + hv.z*w2.x + hv.w*w3.x;
        part[b][1] += hv.x*w0.y + hv.y*w1.y + hv.z*w2.y + hv.w*w3.y;
        part[b][2] += hv.x*w0.z + hv.y*w1.z + hv.z*w2.z + hv.w*w3.z;
        part[b][3] += hv.x*w0.w + hv.y*w1.w + hv.z*w2.w + hv.w*w3.w;
      }
    }

    // park h(p) into LDS (waitcnt auto-inserted here)
    #pragma unroll
    for (int r = 0; r < 8; ++r) {
      const int q = r*256 + tid, b = q >> 7, qh = q & 127;
      float* dst = &hs[b*512 + SWZ(qh)*4];
      *(unsigned long long*)dst       = hld[2*r];
      *(unsigned long long*)(dst + 2) = hld[2*r+1];
    }
    __syncthreads();

    // h @ U  (K = 512, 32 k per thread)
    #pragma unroll
    for (int b = 0; b < 16; ++b) {
      const float* hrow = &hs[b*512];
      #pragma unroll
      for (int i = 0; i < 8; ++i) {
        const int q = kcc*8 + i;
        const float4 hv = *(const float4*)&hrow[SWZ(q)*4];
        const float4 u0 = ureg[i*4+0], u1 = ureg[i*4+1], u2 = ureg[i*4+2], u3 = ureg[i*4+3];
        part[b][0] += hv.x*u0.x + hv.y*u1.x + hv.z*u2.x + hv.w*u3.x;
        part[b][1] += hv.x*u0.y + hv.y*u1.y + hv.z*u2.y + hv.w*u3.y;
        part[b][2] += hv.x*u0.z + hv.y*u1.z + hv.z*u2.z + hv.w*u3.z;
        part[b][3] += hv.x*u0.w + hv.y*u1.w + hv.z*u2.w + hv.w*u3.w;
      }
    }

    // shuffle-tree reduce over the 16 kcc lanes; lane ends with b = kcc.
    // keep = my b's partial, send = partner b's partial (keep/send swap roles).
    const int b0 = lane & 1, b1 = (lane >> 1) & 1, b2 = (lane >> 2) & 1, b3 = (lane >> 3) & 1;
    float r1[8][4], r2[4][4], r3[2][4], z[4];
    #pragma unroll
    for (int i = 0; i < 8; ++i)
      #pragma unroll
      for (int g = 0; g < 4; ++g) {
        const float keep = b0 ? part[2*i+1][g] : part[2*i][g];
        const float send = b0 ? part[2*i][g]   : part[2*i+1][g];
        r1[i][g] = keep + __shfl_xor(send, 1, 64);
      }
    #pragma unroll
    for (int i = 0; i < 4; ++i)
      #pragma unroll
      for (int g = 0; g < 4; ++g) {
        const float keep = b1 ? r1[2*i+1][g] : r1[2*i][g];
        const float send = b1 ? r1[2*i][g]   : r1[2*i+1][g];
        r2[i][g] = keep + __shfl_xor(send, 2, 64);
      }
    #pragma unroll
    for (int i = 0; i < 2; ++i)
      #pragma unroll
      for (int g = 0; g < 4; ++g) {
        const float keep = b2 ? r2[2*i+1][g] : r2[2*i][g];
        const float send = b2 ? r2[2*i][g]   : r2[2*i+1][g];
        r3[i][g] = keep + __shfl_xor(send, 4, 64);
      }
    #pragma unroll
    for (int g = 0; g < 4; ++g) {
      const float keep = b3 ? r3[1][g] : r3[0][g];
      const float send = b3 ? r3[0][g] : r3[1][g];
      z[g] = keep + __shfl_xor(send, 8, 64);
    }

    // gates (Keras order i,f,g,o) for (b = bq*16+kcc, col)
    const float zi = z[0] + breg.x;
    const float zf = z[1] + breg.y;
    const float zg = z[2] + breg.z;
    const float zo = z[3] + breg.w;
    const float ig = 1.f/(1.f + expf(-zi));
    const float fg = 1.f/(1.f + expf(-zf));
    const float tg = tanhf(zg);
    const float og = 1.f/(1.f + expf(-zo));
    cst = fg*cst + ig*tg;
    const float hval = og * tanhf(cst);
    __hip_atomic_store(&hn[(size_t)(bq*16 + kcc)*HH + col], hval,
                       __ATOMIC_RELAXED, __HIP_MEMORY_SCOPE_AGENT);

    // drain stores, then publish readiness (single flag store, no RMW)
    asm volatile("s_waitcnt vmcnt(0)" ::: "memory");
    __syncthreads();
    if (tid == 0)
      __hip_atomic_store(&rdy[cg], (unsigned)(p+1), __ATOMIC_RELAXED, __HIP_MEMORY_SCOPE_AGENT);
  }
}

// ---------------------------------------------------------------------------
// K3: pots[b][t][tag] = [h_fw(t), h_bw(t)] @ wde^T + bde (+ boundaries)
// h layout: [d][phase][b][k]
// ---------------------------------------------------------------------------
__global__ __launch_bounds__(256) void k_dense(
    const float* __restrict__ h_all, const float* __restrict__ wde,
    const float* __restrict__ bde, const float* __restrict__ lb,
    const float* __restrict__ rb, float* __restrict__ pots)
{
  const int wv   = threadIdx.x >> 6;
  const int lane = threadIdx.x & 63;
  const int tok  = blockIdx.x*4 + wv;          // 0..32767
  const int b = tok >> 9, t = tok & 511;
  const float* hf = h_all + (size_t)(t+1)*HSTRIDE + (size_t)b*HH;
  const float* hb = h_all + DSTRIDE + (size_t)(SS-t)*HSTRIDE + (size_t)b*HH;
  float hr[16];
  *(float4*)&hr[0]  = *(const float4*)&hf[lane*8];
  *(float4*)&hr[4]  = *(const float4*)&hf[lane*8+4];
  *(float4*)&hr[8]  = *(const float4*)&hb[lane*8];
  *(float4*)&hr[12] = *(const float4*)&hb[lane*8+4];
  float s[9];
  #pragma unroll
  for (int tg = 0; tg < 9; ++tg) {
    const float* w0 = wde + tg*1024 + lane*8;
    const float* w1 = w0 + 512;
    const float4 a0 = *(const float4*)w0, a1 = *(const float4*)(w0+4);
    const float4 b0 = *(const float4*)w1, b1 = *(const float4*)(w1+4);
    s[tg] = hr[0]*a0.x + hr[1]*a0.y + hr[2]*a0.z + hr[3]*a0.w
          + hr[4]*a1.x + hr[5]*a1.y + hr[6]*a1.z + hr[7]*a1.w
          + hr[8]*b0.x + hr[9]*b0.y + hr[10]*b0.z + hr[11]*b0.w
          + hr[12]*b1.x + hr[13]*b1.y + hr[14]*b1.z + hr[15]*b1.w;
  }
  #pragma unroll
  for (int tg = 0; tg < 9; ++tg) {
    #pragma unroll
    for (int off = 32; off > 0; off >>= 1) s[tg] += __shfl_xor(s[tg], off, 64);
  }
  if (lane < 9) {
    float v = s[lane] + bde[lane];
    if (t == 0)   v += lb[lane];
    if (t == 511) v += rb[lane];
    pots[(size_t)tok*9 + lane] = v;
  }
}

// ---------------------------------------------------------------------------
// K4: Viterbi decode. One wave per batch row.
// ---------------------------------------------------------------------------
__global__ __launch_bounds__(64) void k_viterbi(
    const float* __restrict__ pots, const float* __restrict__ trans,
    float* __restrict__ dec)
{
  const int b = blockIdx.x;
  const int lane = threadIdx.x;
  __shared__ unsigned char bp[511*9];
  __shared__ unsigned char tl[512];
  __shared__ float af[9];
  const float* pb = pots + (size_t)b*512*9;
  float tr[9];
  #pragma unroll
  for (int i = 0; i < 9; ++i) tr[i] = (lane < 9) ? trans[i*9 + lane] : 0.f;
  float alpha = (lane < 9) ? pb[lane] : -3e38f;
  for (int t = 1; t < 512; ++t) {
    float best = -3e38f; int bi = 0;
    #pragma unroll
    for (int i = 0; i < 9; ++i) {
      const float sc = __shfl(alpha, i, 64) + tr[i];
      if (sc > best) { best = sc; bi = i; }     // strict > keeps first max (jnp.argmax)
    }
    if (lane < 9) {
      bp[(t-1)*9 + lane] = (unsigned char)bi;
      alpha = best + pb[(size_t)t*9 + lane];
    }
  }
  if (lane < 9) af[lane] = alpha;
  __syncthreads();
  if (lane == 0) {
    int tg = 0; float bv = af[0];
    #pragma unroll
    for (int i = 1; i < 9; ++i) if (af[i] > bv) { bv = af[i]; tg = i; }
    tl[511] = (unsigned char)tg;
    for (int t = 510; t >= 0; --t) { tg = bp[t*9 + tg]; tl[t] = (unsigned char)tg; }
  }
  __syncthreads();
  for (int t = lane; t < 512; t += 64) dec[(size_t)b*512 + t] = (float)tl[t];
}

// ---------------------------------------------------------------------------
extern "C" void kernel_launch(void* const* d_in, const int* in_sizes, int n_in,
                              void* d_out, int out_size, void* d_ws, size_t ws_size,
                              hipStream_t stream)
{
  const int*   inputs = (const int*)  d_in[0];
  const float* emb    = (const float*)d_in[1];
  const float* Wf     = (const float*)d_in[2];
  const float* Uf     = (const float*)d_in[3];
  const float* bf     = (const float*)d_in[4];
  const float* Wb     = (const float*)d_in[5];
  const float* Ub     = (const float*)d_in[6];
  const float* bb2    = (const float*)d_in[7];
  const float* Wd     = (const float*)d_in[8];
  const float* bd     = (const float*)d_in[9];
  const float* crfW   = (const float*)d_in[10];
  const float* crfb   = (const float*)d_in[11];
  const float* trans  = (const float*)d_in[12];
  const float* lb     = (const float*)d_in[13];
  const float* rb     = (const float*)d_in[14];

  float* ws   = (float*)d_ws;
  unsigned int* bars = (unsigned int*)d_ws;           // first 16 KB: ready flags
  float* hall = ws + 4096;                            // 2*513*32768 floats (~134.5 MB)
  float* wde  = hall + 2*DSTRIDE;                     // 9216 floats
  float* bde  = wde + 9216;                           // 16 floats

  float* dec  = (float*)d_out;                        // 32768 floats
  float* pots = dec + (size_t)BB*SS;                  // 294912 floats

  hipMemsetAsync(d_ws, 0, 16384, stream);
  hipMemsetAsync(hall, 0, (size_t)HSTRIDE*sizeof(float), stream);
  hipMemsetAsync(hall + DSTRIDE, 0, (size_t)HSTRIDE*sizeof(float), stream);

  k_wde<<<36, 256, 0, stream>>>(Wd, bd, crfW, crfb, wde, bde);

  {
    const int*   a0 = inputs; const float* a1 = emb;
    const float* a2 = Uf;  const float* a3 = Ub;
    const float* a4 = Wf;  const float* a5 = Wb;
    const float* a6 = bf;  const float* a7 = bb2;
    float* a8 = hall; unsigned int* a9 = bars;
    void* args[] = { &a0,&a1,&a2,&a3,&a4,&a5,&a6,&a7,&a8,&a9 };
    if (hipLaunchCooperativeKernel((void*)k_lstm, dim3(NWG), dim3(256),
                                   args, 0, stream) != hipSuccess) {
      k_lstm<<<NWG, 256, 0, stream>>>(inputs, emb, Uf, Ub, Wf, Wb, bf, bb2, hall, bars);
    }
  }

  k_dense<<<8192, 256, 0, stream>>>(hall, wde, bde, lb, rb, pots);
  k_viterbi<<<64, 64, 0, stream>>>(pots, trans, dec);
}

// Round 6
// 8251.982 us; speedup vs baseline: 2.9986x; 1.0423x over previous
//
#include <hip/hip_runtime.h>
#include <hip/hip_bf16.h>
#include <math.h>

#define BB 64
#define SS 512
#define EE 256
#define HH 512
#define GG 2048   // 4H
#define NWG 256
#define HSTRIDE 32768                       // floats per phase: 64 b * 512 k
#define DSTRIDE ((size_t)(SS+1)*HSTRIDE)    // floats per direction
#define SWZ(q) ((q) ^ (((q) >> 3) & 7))     // LDS quad swizzle

// ---------------------------------------------------------------------------
// K_pre: fold dense + CRF kernel:  wde[tag][k] = sum_m Wd[k][m]*crfW[m][tag]
// ---------------------------------------------------------------------------
__global__ void k_wde(const float* __restrict__ Wd, const float* __restrict__ bd,
                      const float* __restrict__ crfW, const float* __restrict__ crfb,
                      float* __restrict__ wde, float* __restrict__ bde)
{
  const int idx = blockIdx.x*256 + threadIdx.x;
  if (idx < 9*1024) {
    const int tag = idx >> 10, k = idx & 1023;
    float s = 0.f;
    #pragma unroll
    for (int m = 0; m < 9; ++m) s += Wd[k*9 + m] * crfW[m*9 + tag];
    wde[idx] = s;
  }
  if (idx < 9) {
    float s = crfb[idx];
    #pragma unroll
    for (int m = 0; m < 9; ++m) s += bd[m]*crfW[m*9 + idx];
    bde[idx] = s;
  }
}

// ---------------------------------------------------------------------------
// K2: persistent fused bidirectional LSTM.
// 256 WGs: wg -> group g = wg&7 (d = wg&1, bq = (wg>>1)&3), cg = wg>>3.
// All 32 WGs of a group share wg%8 => same XCD (round-robin dispatch), so
// h hand-off and flags stay in one L2. WG tile = 16 b x 16 h-cols.
// Producer h stores: agent write-through atomics (visible at L3/L2).
// Consumer h loads: PLAIN coalesced float4 (safe: dispatch-start acquire
// invalidates caches; each h address is written once before flag-ordered
// first read => no stale line possible). Flags: agent atomics, no RMW.
// x@W computed before the poll (off critical path); p==0 skips h entirely.
// h layout: h_all[d][phase 1..512][b][k] at slot p+1; slot 0 never touched.
// ---------------------------------------------------------------------------
__global__ __launch_bounds__(256, 1) void k_lstm(
    const int* __restrict__ inputs, const float* __restrict__ emb,
    const float* __restrict__ Uf, const float* __restrict__ Ub,
    const float* __restrict__ Wf, const float* __restrict__ Wb,
    const float* __restrict__ bf, const float* __restrict__ bb2,
    float* __restrict__ h_all, unsigned int* __restrict__ bars)
{
  const int wg = blockIdx.x;
  const int d  = wg & 1;
  const int bq = (wg >> 1) & 3;
  const int cg = wg >> 3;                    // 0..31
  const float* __restrict__ U    = d ? Ub  : Uf;
  const float* __restrict__ W    = d ? Wb  : Wf;
  const float* __restrict__ bias = d ? bb2 : bf;
  float* __restrict__ h_d = h_all + (size_t)d * DSTRIDE;
  unsigned int* __restrict__ rdy = bars + (wg & 7)*64;   // 32 flags / group

  __shared__ float xs[4096];     // [16 b][256 k] quad-swizzled (16 KB)
  __shared__ float hs[8192];     // [16 b][512 k] quad-swizzled (32 KB)
  __shared__ float hst[320];     // [16 b][16 col] stride 20 (out-stage)
  __shared__ int   tok_l[16];

  const int tid  = threadIdx.x;
  const int w    = tid >> 6;
  const int lane = tid & 63;
  const int kcc  = lane & 15;
  const int jj   = lane >> 4;
  const int col  = cg*16 + w*4 + jj;         // this thread's h-column

  // weights in registers: k-split 16-way by kcc
  float4 ureg[32];   // U[k = kcc*32+i][gates ifgo at col]
  #pragma unroll
  for (int i = 0; i < 32; ++i) {
    const float* ur = U + (size_t)(kcc*32 + i)*GG + col;
    ureg[i] = make_float4(ur[0], ur[512], ur[1024], ur[1536]);
  }
  float4 wreg[16];   // W[k = kcc*16+i][gates at col]
  #pragma unroll
  for (int i = 0; i < 16; ++i) {
    const float* wr = W + (size_t)(kcc*16 + i)*GG + col;
    wreg[i] = make_float4(wr[0], wr[512], wr[1024], wr[1536]);
  }
  const float4 breg = make_float4(bias[col], bias[512+col], bias[1024+col], bias[1536+col]);
  float cst = 0.f;                           // c-state for (b = bq*16+kcc, col)

  #pragma unroll 1
  for (int p = 0; p < 512; ++p) {
    const int t = d ? (511 - p) : p;
    const float* __restrict__ hp = h_d + (size_t)p     * HSTRIDE;
    float* __restrict__ hn       = h_d + (size_t)(p+1) * HSTRIDE;

    if (tid < 16) tok_l[tid] = inputs[(bq*16 + tid)*SS + t];
    __syncthreads();                         // tok ready; xs free

    // stage x tile [16][256]
    #pragma unroll
    for (int r = 0; r < 4; ++r) {
      const int q = r*256 + tid, b = q >> 6, qx = q & 63;
      const float4 v = *(const float4*)&emb[(size_t)tok_l[b]*EE + qx*4];
      *(float4*)&xs[b*256 + SWZ(qx)*4] = v;
    }
    __syncthreads();                         // xs ready

    // all waves poll this group's 32 producer flags (h(p) ready)
    if (p) {
      for (;;) {
        unsigned int v = 0xFFFFFFFFu;
        if (lane < 32)
          v = __hip_atomic_load(&rdy[lane], __ATOMIC_RELAXED, __HIP_MEMORY_SCOPE_AGENT);
        if (__all((int)(v >= (unsigned)p))) break;
        __builtin_amdgcn_s_sleep(1);
      }
    }

    // issue h(p) plain coalesced loads (latency hidden by x@W below)
    float4 hld4[8];
    if (p) {
      #pragma unroll
      for (int r = 0; r < 8; ++r) {
        const int q = r*256 + tid, b = q >> 7, qh = q & 127;
        hld4[r] = *(const float4*)&hp[(size_t)(bq*16 + b)*HH + qh*4];
      }
    }

    float part[16][4];
    #pragma unroll
    for (int b = 0; b < 16; ++b) { part[b][0]=0.f; part[b][1]=0.f; part[b][2]=0.f; part[b][3]=0.f; }

    // x @ W  (K = 256, 16 k per thread)
    #pragma unroll
    for (int b = 0; b < 16; ++b) {
      const float* xrow = &xs[b*256];
      #pragma unroll
      for (int i = 0; i < 4; ++i) {
        const int q = kcc*4 + i;
        const float4 hv = *(const float4*)&xrow[SWZ(q)*4];
        const float4 w0 = wreg[i*4+0], w1 = wreg[i*4+1], w2 = wreg[i*4+2], w3 = wreg[i*4+3];
        part[b][0] += hv.x*w0.x + hv.y*w1.x + hv.z*w2.x + hv.w*w3.x;
        part[b][1] += hv.x*w0.y + hv.y*w1.y + hv.z*w2.y + hv.w*w3.y;
        part[b][2] += hv.x*w0.z + hv.y*w1.z + hv.z*w2.z + hv.w*w3.z;
        part[b][3] += hv.x*w0.w + hv.y*w1.w + hv.z*w2.w + hv.w*w3.w;
      }
    }

    if (p) {
      // park h(p) into LDS (vmcnt wait auto-inserted here)
      #pragma unroll
      for (int r = 0; r < 8; ++r) {
        const int q = r*256 + tid, b = q >> 7, qh = q & 127;
        *(float4*)&hs[b*512 + SWZ(qh)*4] = hld4[r];
      }
      __syncthreads();                       // hs ready

      // h @ U  (K = 512, 32 k per thread)
      #pragma unroll
      for (int b = 0; b < 16; ++b) {
        const float* hrow = &hs[b*512];
        #pragma unroll
        for (int i = 0; i < 8; ++i) {
          const int q = kcc*8 + i;
          const float4 hv = *(const float4*)&hrow[SWZ(q)*4];
          const float4 u0 = ureg[i*4+0], u1 = ureg[i*4+1], u2 = ureg[i*4+2], u3 = ureg[i*4+3];
          part[b][0] += hv.x*u0.x + hv.y*u1.x + hv.z*u2.x + hv.w*u3.x;
          part[b][1] += hv.x*u0.y + hv.y*u1.y + hv.z*u2.y + hv.w*u3.y;
          part[b][2] += hv.x*u0.z + hv.y*u1.z + hv.z*u2.z + hv.w*u3.z;
          part[b][3] += hv.x*u0.w + hv.y*u1.w + hv.z*u2.w + hv.w*u3.w;
        }
      }
    }

    // shuffle-tree reduce over 16 kcc lanes; lane ends with b = kcc.
    const int b0 = lane & 1, b1 = (lane >> 1) & 1, b2 = (lane >> 2) & 1, b3 = (lane >> 3) & 1;
    float r1[8][4], r2[4][4], r3[2][4], z[4];
    #pragma unroll
    for (int i = 0; i < 8; ++i)
      #pragma unroll
      for (int g = 0; g < 4; ++g) {
        const float keep = b0 ? part[2*i+1][g] : part[2*i][g];
        const float send = b0 ? part[2*i][g]   : part[2*i+1][g];
        r1[i][g] = keep + __shfl_xor(send, 1, 64);
      }
    #pragma unroll
    for (int i = 0; i < 4; ++i)
      #pragma unroll
      for (int g = 0; g < 4; ++g) {
        const float keep = b1 ? r1[2*i+1][g] : r1[2*i][g];
        const float send = b1 ? r1[2*i][g]   : r1[2*i+1][g];
        r2[i][g] = keep + __shfl_xor(send, 2, 64);
      }
    #pragma unroll
    for (int i = 0; i < 2; ++i)
      #pragma unroll
      for (int g = 0; g < 4; ++g) {
        const float keep = b2 ? r2[2*i+1][g] : r2[2*i][g];
        const float send = b2 ? r2[2*i][g]   : r2[2*i+1][g];
        r3[i][g] = keep + __shfl_xor(send, 4, 64);
      }
    #pragma unroll
    for (int g = 0; g < 4; ++g) {
      const float keep = b3 ? r3[1][g] : r3[0][g];
      const float send = b3 ? r3[0][g] : r3[1][g];
      z[g] = keep + __shfl_xor(send, 8, 64);
    }

    // gates (Keras order i,f,g,o) for (b = bq*16+kcc, col)
    const float zi = z[0] + breg.x;
    const float zf = z[1] + breg.y;
    const float zg = z[2] + breg.z;
    const float zo = z[3] + breg.w;
    const float ig = 1.f/(1.f + expf(-zi));
    const float fg = 1.f/(1.f + expf(-zf));
    const float tg = tanhf(zg);
    const float og = 1.f/(1.f + expf(-zo));
    cst = fg*cst + ig*tg;
    const float hval = og * tanhf(cst);

    // stage output tile in LDS, then coalesced agent stores (16B spans)
    hst[kcc*20 + w*4 + jj] = hval;
    __syncthreads();
    if (tid < 64) {
      const int b = tid >> 2, c = tid & 3;
      const float4 v = *(const float4*)&hst[b*20 + c*4];
      unsigned long long lo, hi;
      __builtin_memcpy(&lo, &v.x, 8);
      __builtin_memcpy(&hi, &v.z, 8);
      unsigned long long* dst = (unsigned long long*)&hn[(size_t)(bq*16 + b)*HH + cg*16 + c*4];
      __hip_atomic_store(dst,     lo, __ATOMIC_RELAXED, __HIP_MEMORY_SCOPE_AGENT);
      __hip_atomic_store(dst + 1, hi, __ATOMIC_RELAXED, __HIP_MEMORY_SCOPE_AGENT);
    }

    // drain stores, then publish readiness (single flag store, no RMW)
    asm volatile("s_waitcnt vmcnt(0)" ::: "memory");
    __syncthreads();
    if (tid == 0)
      __hip_atomic_store(&rdy[cg], (unsigned)(p+1), __ATOMIC_RELAXED, __HIP_MEMORY_SCOPE_AGENT);
  }
}

// ---------------------------------------------------------------------------
// K3: pots[b][t][tag] = [h_fw(t), h_bw(t)] @ wde^T + bde (+ boundaries)
// h layout: [d][phase][b][k]
// ---------------------------------------------------------------------------
__global__ __launch_bounds__(256) void k_dense(
    const float* __restrict__ h_all, const float* __restrict__ wde,
    const float* __restrict__ bde, const float* __restrict__ lb,
    const float* __restrict__ rb, float* __restrict__ pots)
{
  const int wv   = threadIdx.x >> 6;
  const int lane = threadIdx.x & 63;
  const int tok  = blockIdx.x*4 + wv;          // 0..32767
  const int b = tok >> 9, t = tok & 511;
  const float* hf = h_all + (size_t)(t+1)*HSTRIDE + (size_t)b*HH;
  const float* hb = h_all + DSTRIDE + (size_t)(SS-t)*HSTRIDE + (size_t)b*HH;
  float hr[16];
  *(float4*)&hr[0]  = *(const float4*)&hf[lane*8];
  *(float4*)&hr[4]  = *(const float4*)&hf[lane*8+4];
  *(float4*)&hr[8]  = *(const float4*)&hb[lane*8];
  *(float4*)&hr[12] = *(const float4*)&hb[lane*8+4];
  float s[9];
  #pragma unroll
  for (int tg = 0; tg < 9; ++tg) {
    const float* w0 = wde + tg*1024 + lane*8;
    const float* w1 = w0 + 512;
    const float4 a0 = *(const float4*)w0, a1 = *(const float4*)(w0+4);
    const float4 b0 = *(const float4*)w1, b1 = *(const float4*)(w1+4);
    s[tg] = hr[0]*a0.x + hr[1]*a0.y + hr[2]*a0.z + hr[3]*a0.w
          + hr[4]*a1.x + hr[5]*a1.y + hr[6]*a1.z + hr[7]*a1.w
          + hr[8]*b0.x + hr[9]*b0.y + hr[10]*b0.z + hr[11]*b0.w
          + hr[12]*b1.x + hr[13]*b1.y + hr[14]*b1.z + hr[15]*b1.w;
  }
  #pragma unroll
  for (int tg = 0; tg < 9; ++tg) {
    #pragma unroll
    for (int off = 32; off > 0; off >>= 1) s[tg] += __shfl_xor(s[tg], off, 64);
  }
  if (lane < 9) {
    float v = s[lane] + bde[lane];
    if (t == 0)   v += lb[lane];
    if (t == 511) v += rb[lane];
    pots[(size_t)tok*9 + lane] = v;
  }
}

// ---------------------------------------------------------------------------
// K4: Viterbi decode. One wave per batch row.
// ---------------------------------------------------------------------------
__global__ __launch_bounds__(64) void k_viterbi(
    const float* __restrict__ pots, const float* __restrict__ trans,
    float* __restrict__ dec)
{
  const int b = blockIdx.x;
  const int lane = threadIdx.x;
  __shared__ unsigned char bp[511*9];
  __shared__ unsigned char tl[512];
  __shared__ float af[9];
  const float* pb = pots + (size_t)b*512*9;
  float tr[9];
  #pragma unroll
  for (int i = 0; i < 9; ++i) tr[i] = (lane < 9) ? trans[i*9 + lane] : 0.f;
  float alpha = (lane < 9) ? pb[lane] : -3e38f;
  for (int t = 1; t < 512; ++t) {
    float best = -3e38f; int bi = 0;
    #pragma unroll
    for (int i = 0; i < 9; ++i) {
      const float sc = __shfl(alpha, i, 64) + tr[i];
      if (sc > best) { best = sc; bi = i; }     // strict > keeps first max (jnp.argmax)
    }
    if (lane < 9) {
      bp[(t-1)*9 + lane] = (unsigned char)bi;
      alpha = best + pb[(size_t)t*9 + lane];
    }
  }
  if (lane < 9) af[lane] = alpha;
  __syncthreads();
  if (lane == 0) {
    int tg = 0; float bv = af[0];
    #pragma unroll
    for (int i = 1; i < 9; ++i) if (af[i] > bv) { bv = af[i]; tg = i; }
    tl[511] = (unsigned char)tg;
    for (int t = 510; t >= 0; --t) { tg = bp[t*9 + tg]; tl[t] = (unsigned char)tg; }
  }
  __syncthreads();
  for (int t = lane; t < 512; t += 64) dec[(size_t)b*512 + t] = (float)tl[t];
}

// ---------------------------------------------------------------------------
extern "C" void kernel_launch(void* const* d_in, const int* in_sizes, int n_in,
                              void* d_out, int out_size, void* d_ws, size_t ws_size,
                              hipStream_t stream)
{
  const int*   inputs = (const int*)  d_in[0];
  const float* emb    = (const float*)d_in[1];
  const float* Wf     = (const float*)d_in[2];
  const float* Uf     = (const float*)d_in[3];
  const float* bf     = (const float*)d_in[4];
  const float* Wb     = (const float*)d_in[5];
  const float* Ub     = (const float*)d_in[6];
  const float* bb2    = (const float*)d_in[7];
  const float* Wd     = (const float*)d_in[8];
  const float* bd     = (const float*)d_in[9];
  const float* crfW   = (const float*)d_in[10];
  const float* crfb   = (const float*)d_in[11];
  const float* trans  = (const float*)d_in[12];
  const float* lb     = (const float*)d_in[13];
  const float* rb     = (const float*)d_in[14];

  float* ws   = (float*)d_ws;
  unsigned int* bars = (unsigned int*)d_ws;           // first 16 KB: ready flags
  float* hall = ws + 4096;                            // 2*513*32768 floats (~134.5 MB)
  float* wde  = hall + 2*DSTRIDE;                     // 9216 floats
  float* bde  = wde + 9216;                           // 16 floats

  float* dec  = (float*)d_out;                        // 32768 floats
  float* pots = dec + (size_t)BB*SS;                  // 294912 floats

  hipMemsetAsync(d_ws, 0, 16384, stream);

  k_wde<<<36, 256, 0, stream>>>(Wd, bd, crfW, crfb, wde, bde);

  {
    const int*   a0 = inputs; const float* a1 = emb;
    const float* a2 = Uf;  const float* a3 = Ub;
    const float* a4 = Wf;  const float* a5 = Wb;
    const float* a6 = bf;  const float* a7 = bb2;
    float* a8 = hall; unsigned int* a9 = bars;
    void* args[] = { &a0,&a1,&a2,&a3,&a4,&a5,&a6,&a7,&a8,&a9 };
    if (hipLaunchCooperativeKernel((void*)k_lstm, dim3(NWG), dim3(256),
                                   args, 0, stream) != hipSuccess) {
      k_lstm<<<NWG, 256, 0, stream>>>(inputs, emb, Uf, Ub, Wf, Wb, bf, bb2, hall, bars);
    }
  }

  k_dense<<<8192, 256, 0, stream>>>(hall, wde, bde, lb, rb, pots);
  k_viterbi<<<64, 64, 0, stream>>>(pots, trans, dec);
}

// Round 7
// 7997.102 us; speedup vs baseline: 3.0942x; 1.0319x over previous
//
#include <hip/hip_runtime.h>
#include <hip/hip_bf16.h>
#include <math.h>

#define BB 64
#define SS 512
#define EE 256
#define HH 512
#define GG 2048   // 4H
#define NWG 256
#define HSTRIDE 32768                       // floats per phase: 64 b * 512 k
#define DSTRIDE ((size_t)(SS+1)*HSTRIDE)    // floats per direction
#define SWZ(q) ((q) ^ (((q) >> 3) & 7))     // LDS quad swizzle

// ---------------------------------------------------------------------------
// K_pre: fold dense + CRF kernel:  wde[tag][k] = sum_m Wd[k][m]*crfW[m][tag]
// ---------------------------------------------------------------------------
__global__ void k_wde(const float* __restrict__ Wd, const float* __restrict__ bd,
                      const float* __restrict__ crfW, const float* __restrict__ crfb,
                      float* __restrict__ wde, float* __restrict__ bde)
{
  const int idx = blockIdx.x*256 + threadIdx.x;
  if (idx < 9*1024) {
    const int tag = idx >> 10, k = idx & 1023;
    float s = 0.f;
    #pragma unroll
    for (int m = 0; m < 9; ++m) s += Wd[k*9 + m] * crfW[m*9 + tag];
    wde[idx] = s;
  }
  if (idx < 9) {
    float s = crfb[idx];
    #pragma unroll
    for (int m = 0; m < 9; ++m) s += bd[m]*crfW[m*9 + idx];
    bde[idx] = s;
  }
}

// ---------------------------------------------------------------------------
// K2: persistent fused bidirectional LSTM.
// 256 WGs: wg -> group g = wg&7 (d = wg&1, bq = (wg>>1)&3), cg = wg>>3.
// Group's 32 WGs share wg%8 -> likely same XCD. WG tile = 16 b x 16 h-cols.
// Producer h stores: 4-B relaxed agent atomics (write-through, proven
// amplification-free in R5), LDS-staged so a wave emits 4 x 64-B spans.
// Consumer h loads: plain coalesced float4 (ordered behind wave-0 poll +
// __syncthreads). Flags: one 4-B relaxed agent store per WG, wave-0 poll.
// h layout: h_all[d][phase 1..512][b][k]; phase-0 slot never touched.
// ---------------------------------------------------------------------------
__global__ __launch_bounds__(256, 1) void k_lstm(
    const int* __restrict__ inputs, const float* __restrict__ emb,
    const float* __restrict__ Uf, const float* __restrict__ Ub,
    const float* __restrict__ Wf, const float* __restrict__ Wb,
    const float* __restrict__ bf, const float* __restrict__ bb2,
    float* __restrict__ h_all, unsigned int* __restrict__ bars)
{
  const int wg = blockIdx.x;
  const int d  = wg & 1;
  const int bq = (wg >> 1) & 3;
  const int cg = wg >> 3;                    // 0..31
  const float* __restrict__ U    = d ? Ub  : Uf;
  const float* __restrict__ W    = d ? Wb  : Wf;
  const float* __restrict__ bias = d ? bb2 : bf;
  float* __restrict__ h_d = h_all + (size_t)d * DSTRIDE;
  unsigned int* __restrict__ rdy = bars + (wg & 7)*64;   // 32 flags / group

  __shared__ float xs[4096];     // [16 b][256 k] quad-swizzled (16 KB)
  __shared__ float hs[8192];     // [16 b][512 k] quad-swizzled (32 KB)
  __shared__ float hst[272];     // [16 b][16 col] stride 17 (out-stage)
  __shared__ int   tok_l[16];

  const int tid  = threadIdx.x;
  const int w    = tid >> 6;
  const int lane = tid & 63;
  const int kcc  = lane & 15;
  const int jj   = lane >> 4;
  const int col  = cg*16 + w*4 + jj;         // this thread's h-column

  // weights in registers: k-split 16-way by kcc
  float4 ureg[32];   // U[k = kcc*32+i][gates ifgo at col]
  #pragma unroll
  for (int i = 0; i < 32; ++i) {
    const float* ur = U + (size_t)(kcc*32 + i)*GG + col;
    ureg[i] = make_float4(ur[0], ur[512], ur[1024], ur[1536]);
  }
  float4 wreg[16];   // W[k = kcc*16+i][gates at col]
  #pragma unroll
  for (int i = 0; i < 16; ++i) {
    const float* wr = W + (size_t)(kcc*16 + i)*GG + col;
    wreg[i] = make_float4(wr[0], wr[512], wr[1024], wr[1536]);
  }
  const float4 breg = make_float4(bias[col], bias[512+col], bias[1024+col], bias[1536+col]);
  float cst = 0.f;                           // c-state for (b = bq*16+kcc, col)

  #pragma unroll 1
  for (int p = 0; p < 512; ++p) {
    const int t = d ? (511 - p) : p;
    const float* __restrict__ hp = h_d + (size_t)p     * HSTRIDE;
    float* __restrict__ hn       = h_d + (size_t)(p+1) * HSTRIDE;

    if (tid < 16) tok_l[tid] = inputs[(bq*16 + tid)*SS + t];
    __syncthreads();                         // tok ready; xs/hst free

    // stage x tile [16][256]
    #pragma unroll
    for (int r = 0; r < 4; ++r) {
      const int q = r*256 + tid, b = q >> 6, qx = q & 63;
      const float4 v = *(const float4*)&emb[(size_t)tok_l[b]*EE + qx*4];
      *(float4*)&xs[b*256 + SWZ(qx)*4] = v;
    }
    __syncthreads();                         // xs ready

    // wave 0 polls this group's 32 producer flags (h(p) ready)
    if (p) {
      if (w == 0) {
        for (;;) {
          unsigned int v = 0xFFFFFFFFu;
          if (lane < 32)
            v = __hip_atomic_load(&rdy[lane], __ATOMIC_RELAXED, __HIP_MEMORY_SCOPE_AGENT);
          if (__all((int)(v >= (unsigned)p))) break;
          __builtin_amdgcn_s_sleep(1);
        }
      }
      __syncthreads();                       // h(p) visible; orders loads below
    }

    // issue h(p) plain coalesced loads (latency hidden by x@W below)
    float4 hld4[8];
    if (p) {
      #pragma unroll
      for (int r = 0; r < 8; ++r) {
        const int q = r*256 + tid, b = q >> 7, qh = q & 127;
        hld4[r] = *(const float4*)&hp[(size_t)(bq*16 + b)*HH + qh*4];
      }
    }

    float part[16][4];
    #pragma unroll
    for (int b = 0; b < 16; ++b) { part[b][0]=0.f; part[b][1]=0.f; part[b][2]=0.f; part[b][3]=0.f; }

    // x @ W  (K = 256, 16 k per thread)
    #pragma unroll
    for (int b = 0; b < 16; ++b) {
      const float* xrow = &xs[b*256];
      #pragma unroll
      for (int i = 0; i < 4; ++i) {
        const int q = kcc*4 + i;
        const float4 hv = *(const float4*)&xrow[SWZ(q)*4];
        const float4 w0 = wreg[i*4+0], w1 = wreg[i*4+1], w2 = wreg[i*4+2], w3 = wreg[i*4+3];
        part[b][0] += hv.x*w0.x + hv.y*w1.x + hv.z*w2.x + hv.w*w3.x;
        part[b][1] += hv.x*w0.y + hv.y*w1.y + hv.z*w2.y + hv.w*w3.y;
        part[b][2] += hv.x*w0.z + hv.y*w1.z + hv.z*w2.z + hv.w*w3.z;
        part[b][3] += hv.x*w0.w + hv.y*w1.w + hv.z*w2.w + hv.w*w3.w;
      }
    }

    if (p) {
      // park h(p) into LDS (vmcnt wait auto-inserted here)
      #pragma unroll
      for (int r = 0; r < 8; ++r) {
        const int q = r*256 + tid, b = q >> 7, qh = q & 127;
        *(float4*)&hs[b*512 + SWZ(qh)*4] = hld4[r];
      }
      __syncthreads();                       // hs ready

      // h @ U  (K = 512, 32 k per thread)
      #pragma unroll
      for (int b = 0; b < 16; ++b) {
        const float* hrow = &hs[b*512];
        #pragma unroll
        for (int i = 0; i < 8; ++i) {
          const int q = kcc*8 + i;
          const float4 hv = *(const float4*)&hrow[SWZ(q)*4];
          const float4 u0 = ureg[i*4+0], u1 = ureg[i*4+1], u2 = ureg[i*4+2], u3 = ureg[i*4+3];
          part[b][0] += hv.x*u0.x + hv.y*u1.x + hv.z*u2.x + hv.w*u3.x;
          part[b][1] += hv.x*u0.y + hv.y*u1.y + hv.z*u2.y + hv.w*u3.y;
          part[b][2] += hv.x*u0.z + hv.y*u1.z + hv.z*u2.z + hv.w*u3.z;
          part[b][3] += hv.x*u0.w + hv.y*u1.w + hv.z*u2.w + hv.w*u3.w;
        }
      }
    }

    // shuffle-tree reduce over 16 kcc lanes; lane ends with b = kcc.
    const int b0 = lane & 1, b1 = (lane >> 1) & 1, b2 = (lane >> 2) & 1, b3 = (lane >> 3) & 1;
    float r1[8][4], r2[4][4], r3[2][4], z[4];
    #pragma unroll
    for (int i = 0; i < 8; ++i)
      #pragma unroll
      for (int g = 0; g < 4; ++g) {
        const float keep = b0 ? part[2*i+1][g] : part[2*i][g];
        const float send = b0 ? part[2*i][g]   : part[2*i+1][g];
        r1[i][g] = keep + __shfl_xor(send, 1, 64);
      }
    #pragma unroll
    for (int i = 0; i < 4; ++i)
      #pragma unroll
      for (int g = 0; g < 4; ++g) {
        const float keep = b1 ? r1[2*i+1][g] : r1[2*i][g];
        const float send = b1 ? r1[2*i][g]   : r1[2*i+1][g];
        r2[i][g] = keep + __shfl_xor(send, 2, 64);
      }
    #pragma unroll
    for (int i = 0; i < 2; ++i)
      #pragma unroll
      for (int g = 0; g < 4; ++g) {
        const float keep = b2 ? r2[2*i+1][g] : r2[2*i][g];
        const float send = b2 ? r2[2*i][g]   : r2[2*i+1][g];
        r3[i][g] = keep + __shfl_xor(send, 4, 64);
      }
    #pragma unroll
    for (int g = 0; g < 4; ++g) {
      const float keep = b3 ? r3[1][g] : r3[0][g];
      const float send = b3 ? r3[0][g] : r3[1][g];
      z[g] = keep + __shfl_xor(send, 8, 64);
    }

    // gates (Keras order i,f,g,o) for (b = bq*16+kcc, col)
    const float zi = z[0] + breg.x;
    const float zf = z[1] + breg.y;
    const float zg = z[2] + breg.z;
    const float zo = z[3] + breg.w;
    const float ig = 1.f/(1.f + expf(-zi));
    const float fg = 1.f/(1.f + expf(-zf));
    const float tg = tanhf(zg);
    const float og = 1.f/(1.f + expf(-zo));
    cst = fg*cst + ig*tg;
    const float hval = og * tanhf(cst);

    // stage output tile in LDS, then coalesced 4-B agent stores
    hst[kcc*17 + w*4 + jj] = hval;
    __syncthreads();
    {
      const int b = tid >> 4, c = tid & 15;   // wave = 4 rows x 64-B spans
      __hip_atomic_store(&hn[(size_t)(bq*16 + b)*HH + cg*16 + c], hst[b*17 + c],
                         __ATOMIC_RELAXED, __HIP_MEMORY_SCOPE_AGENT);
    }

    // drain stores, then publish readiness (single flag store, no RMW)
    asm volatile("s_waitcnt vmcnt(0)" ::: "memory");
    __syncthreads();
    if (tid == 0)
      __hip_atomic_store(&rdy[cg], (unsigned)(p+1), __ATOMIC_RELAXED, __HIP_MEMORY_SCOPE_AGENT);
  }
}

// ---------------------------------------------------------------------------
// K3: pots[b][t][tag] = [h_fw(t), h_bw(t)] @ wde^T + bde (+ boundaries)
// h layout: [d][phase][b][k]
// ---------------------------------------------------------------------------
__global__ __launch_bounds__(256) void k_dense(
    const float* __restrict__ h_all, const float* __restrict__ wde,
    const float* __restrict__ bde, const float* __restrict__ lb,
    const float* __restrict__ rb, float* __restrict__ pots)
{
  const int wv   = threadIdx.x >> 6;
  const int lane = threadIdx.x & 63;
  const int tok  = blockIdx.x*4 + wv;          // 0..32767
  const int b = tok >> 9, t = tok & 511;
  const float* hf = h_all + (size_t)(t+1)*HSTRIDE + (size_t)b*HH;
  const float* hb = h_all + DSTRIDE + (size_t)(SS-t)*HSTRIDE + (size_t)b*HH;
  float hr[16];
  *(float4*)&hr[0]  = *(const float4*)&hf[lane*8];
  *(float4*)&hr[4]  = *(const float4*)&hf[lane*8+4];
  *(float4*)&hr[8]  = *(const float4*)&hb[lane*8];
  *(float4*)&hr[12] = *(const float4*)&hb[lane*8+4];
  float s[9];
  #pragma unroll
  for (int tg = 0; tg < 9; ++tg) {
    const float* w0 = wde + tg*1024 + lane*8;
    const float* w1 = w0 + 512;
    const float4 a0 = *(const float4*)w0, a1 = *(const float4*)(w0+4);
    const float4 b0 = *(const float4*)w1, b1 = *(const float4*)(w1+4);
    s[tg] = hr[0]*a0.x + hr[1]*a0.y + hr[2]*a0.z + hr[3]*a0.w
          + hr[4]*a1.x + hr[5]*a1.y + hr[6]*a1.z + hr[7]*a1.w
          + hr[8]*b0.x + hr[9]*b0.y + hr[10]*b0.z + hr[11]*b0.w
          + hr[12]*b1.x + hr[13]*b1.y + hr[14]*b1.z + hr[15]*b1.w;
  }
  #pragma unroll
  for (int tg = 0; tg < 9; ++tg) {
    #pragma unroll
    for (int off = 32; off > 0; off >>= 1) s[tg] += __shfl_xor(s[tg], off, 64);
  }
  if (lane < 9) {
    float v = s[lane] + bde[lane];
    if (t == 0)   v += lb[lane];
    if (t == 511) v += rb[lane];
    pots[(size_t)tok*9 + lane] = v;
  }
}

// ---------------------------------------------------------------------------
// K4: Viterbi decode. One wave per batch row.
// ---------------------------------------------------------------------------
__global__ __launch_bounds__(64) void k_viterbi(
    const float* __restrict__ pots, const float* __restrict__ trans,
    float* __restrict__ dec)
{
  const int b = blockIdx.x;
  const int lane = threadIdx.x;
  __shared__ unsigned char bp[511*9];
  __shared__ unsigned char tl[512];
  __shared__ float af[9];
  const float* pb = pots + (size_t)b*512*9;
  float tr[9];
  #pragma unroll
  for (int i = 0; i < 9; ++i) tr[i] = (lane < 9) ? trans[i*9 + lane] : 0.f;
  float alpha = (lane < 9) ? pb[lane] : -3e38f;
  for (int t = 1; t < 512; ++t) {
    float best = -3e38f; int bi = 0;
    #pragma unroll
    for (int i = 0; i < 9; ++i) {
      const float sc = __shfl(alpha, i, 64) + tr[i];
      if (sc > best) { best = sc; bi = i; }     // strict > keeps first max (jnp.argmax)
    }
    if (lane < 9) {
      bp[(t-1)*9 + lane] = (unsigned char)bi;
      alpha = best + pb[(size_t)t*9 + lane];
    }
  }
  if (lane < 9) af[lane] = alpha;
  __syncthreads();
  if (lane == 0) {
    int tg = 0; float bv = af[0];
    #pragma unroll
    for (int i = 1; i < 9; ++i) if (af[i] > bv) { bv = af[i]; tg = i; }
    tl[511] = (unsigned char)tg;
    for (int t = 510; t >= 0; --t) { tg = bp[t*9 + tg]; tl[t] = (unsigned char)tg; }
  }
  __syncthreads();
  for (int t = lane; t < 512; t += 64) dec[(size_t)b*512 + t] = (float)tl[t];
}

// ---------------------------------------------------------------------------
extern "C" void kernel_launch(void* const* d_in, const int* in_sizes, int n_in,
                              void* d_out, int out_size, void* d_ws, size_t ws_size,
                              hipStream_t stream)
{
  const int*   inputs = (const int*)  d_in[0];
  const float* emb    = (const float*)d_in[1];
  const float* Wf     = (const float*)d_in[2];
  const float* Uf     = (const float*)d_in[3];
  const float* bf     = (const float*)d_in[4];
  const float* Wb     = (const float*)d_in[5];
  const float* Ub     = (const float*)d_in[6];
  const float* bb2    = (const float*)d_in[7];
  const float* Wd     = (const float*)d_in[8];
  const float* bd     = (const float*)d_in[9];
  const float* crfW   = (const float*)d_in[10];
  const float* crfb   = (const float*)d_in[11];
  const float* trans  = (const float*)d_in[12];
  const float* lb     = (const float*)d_in[13];
  const float* rb     = (const float*)d_in[14];

  float* ws   = (float*)d_ws;
  unsigned int* bars = (unsigned int*)d_ws;           // first 16 KB: ready flags
  float* hall = ws + 4096;                            // 2*513*32768 floats (~134.5 MB)
  float* wde  = hall + 2*DSTRIDE;                     // 9216 floats
  float* bde  = wde + 9216;                           // 16 floats

  float* dec  = (float*)d_out;                        // 32768 floats
  float* pots = dec + (size_t)BB*SS;                  // 294912 floats

  hipMemsetAsync(d_ws, 0, 16384, stream);

  k_wde<<<36, 256, 0, stream>>>(Wd, bd, crfW, crfb, wde, bde);

  {
    const int*   a0 = inputs; const float* a1 = emb;
    const float* a2 = Uf;  const float* a3 = Ub;
    const float* a4 = Wf;  const float* a5 = Wb;
    const float* a6 = bf;  const float* a7 = bb2;
    float* a8 = hall; unsigned int* a9 = bars;
    void* args[] = { &a0,&a1,&a2,&a3,&a4,&a5,&a6,&a7,&a8,&a9 };
    if (hipLaunchCooperativeKernel((void*)k_lstm, dim3(NWG), dim3(256),
                                   args, 0, stream) != hipSuccess) {
      k_lstm<<<NWG, 256, 0, stream>>>(inputs, emb, Uf, Ub, Wf, Wb, bf, bb2, hall, bars);
    }
  }

  k_dense<<<8192, 256, 0, stream>>>(hall, wde, bde, lb, rb, pots);
  k_viterbi<<<64, 64, 0, stream>>>(pots, trans, dec);
}